// Round 6
// baseline (904.106 us; speedup 1.0000x reference)
//
#include <hip/hip_runtime.h>
#include <stdint.h>

static constexpr int T_STEPS = 15;
static constexpr int C_IN = 6;
static constexpr int C_OUT = 64;
static constexpr int H = 256;
static constexpr int W = 256;
static constexpr int NPOS = H * W;            // 65536
static constexpr int NTAP = 150;              // 6*5*5
#define DTHRESH 15.0

typedef float vfloat4 __attribute__((ext_vector_type(4)));

// workspace layout (bytes)
static constexpr size_t WS_FT     = 0;                              // uint8 [C_IN*NPOS]
static constexpr size_t WS_SERIES = 393216;                         // float [NPOS*16]
static constexpr size_t WS_WINC   = WS_SERIES + (size_t)NPOS*16*4;  // int8  [NPOS]
static constexpr size_t WS_NMAP   = WS_WINC + (size_t)NPOS;         // uint8 [NPOS]
static constexpr size_t WS_VAL    = WS_NMAP + (size_t)NPOS;         // double[NPOS]
static constexpr size_t WS_NEED   = WS_VAL + (size_t)NPOS*8;

// ---------------- K1: first-spike-time map ----------------
__global__ __launch_bounds__(256) void ft_kernel(const float* __restrict__ x,
                                                 uint8_t* __restrict__ ft) {
    int i = blockIdx.x * 256 + threadIdx.x;
    if (i >= C_IN * NPOS) return;
    int f = 15;
    #pragma unroll
    for (int t = T_STEPS - 1; t >= 0; --t) {
        if (x[(size_t)t * (C_IN * NPOS) + i] > 0.0f) f = t;
    }
    ft[i] = (uint8_t)f;
}

// ---------------- K2: per-position conv-as-sorted-accumulate + pointwise WTA ----------------
// One wave per (h,w); lane = output channel. Block = 4 waves, 16 consecutive w.
// LDS: 38400 + 600 + 256 + 1600 = 40856 B -> 4 blocks/CU (163,424 <= 163,840).
__global__ __launch_bounds__(256, 4) void conv_kernel(
        const float* __restrict__ w1, const uint8_t* __restrict__ ftg,
        float* __restrict__ series_ws, int8_t* __restrict__ winc_ws,
        uint8_t* __restrict__ nmap_ws, double* __restrict__ val_ws)
{
    __shared__ float w_lds[NTAP * 64];                       // [tap][o], stride-1 across lanes
    __shared__ uint8_t ft_lds[6 * 5 * 20];                   // [c][kh][col 0..19]
    __shared__ alignas(16) unsigned cnt_lds[4][16];          // per-wave
    __shared__ alignas(16) unsigned short sorted_lds[4][200];// per-wave, 4-aligned buckets

    int tid = threadIdx.x;
    int bid = blockIdx.x;                        // 0..4095
    int h  = bid >> 4;
    int w0 = (bid & 15) << 4;

    // stage weights transposed: w_lds[tap*64 + o] = w1[o*150 + tap] (coalesced reads)
    for (int i = tid; i < C_OUT * NTAP; i += 256) {
        int o = i / NTAP;
        int tap = i - o * NTAP;
        w_lds[tap * 64 + o] = w1[i];
    }
    // stage ft tile with pad-of-15 (never spikes) outside the image
    for (int i = tid; i < 600; i += 256) {
        int c = i / 100;
        int r = i - c * 100;
        int kh = r / 20;
        int j  = r - kh * 20;
        int gh = h - 2 + kh;
        int gw = w0 - 2 + j;
        uint8_t v = 15;
        if (gh >= 0 && gh < H && gw >= 0 && gw < W) v = ftg[c * NPOS + gh * W + gw];
        ft_lds[(c * 5 + kh) * 20 + j] = v;
    }
    __syncthreads();   // the ONLY block barrier

    int lane = tid & 63;
    int wvi  = tid >> 6;
    unsigned* cnt = cnt_lds[wvi];
    unsigned short* srt = sorted_lds[wvi];

    for (int iter = 0; iter < 4; ++iter) {
        int xl = iter * 4 + wvi;                 // local col 0..15
        int p  = h * W + w0 + xl;

        if (lane < 16) cnt[lane] = 0;            // wave-private, no barrier

        // counting sort of the 150 taps by first-spike time (3 tap slots per lane)
        int tap0 = lane, tap1 = lane + 64, tap2 = lane + 128;
        auto ftv = [&](int tap) -> unsigned {
            int c = tap / 25;
            int r = tap - c * 25;
            int kh = r / 5;
            int kw = r - kh * 5;
            return ft_lds[(c * 5 + kh) * 20 + xl + kw];
        };
        unsigned f0 = ftv(tap0);
        unsigned f1 = ftv(tap1);
        unsigned f2 = (tap2 < NTAP) ? ftv(tap2) : 15u;
        unsigned r0 = 0, r1 = 0, r2 = 0;
        if (f0 < 15u) r0 = atomicAdd(&cnt[f0], 1u);
        if (f1 < 15u) r1 = atomicAdd(&cnt[f1], 1u);
        if (f2 < 15u) r2 = atomicAdd(&cnt[f2], 1u);

        // read all 16 counts via 4 vector loads (broadcast)
        uint4 c4[4];
        #pragma unroll
        for (int i = 0; i < 4; ++i) c4[i] = ((const uint4*)cnt)[i];
        unsigned cv_t[16];
        #pragma unroll
        for (int i = 0; i < 4; ++i) {
            cv_t[4*i+0] = c4[i].x; cv_t[4*i+1] = c4[i].y;
            cv_t[4*i+2] = c4[i].z; cv_t[4*i+3] = c4[i].w;
        }
        int kt[15];
        #pragma unroll
        for (int t = 0; t < 15; ++t) kt[t] = (int)__builtin_amdgcn_readfirstlane(cv_t[t]);

        // aligned-4 bucket starts: per-lane predicated prefix of align4(counts)
        unsigned st0 = 0, st1 = 0, st2 = 0;
        #pragma unroll
        for (int t = 0; t < 15; ++t) {
            unsigned a = (cv_t[t] + 3u) & ~3u;
            if ((unsigned)t < f0) st0 += a;
            if ((unsigned)t < f1) st1 += a;
            if ((unsigned)t < f2) st2 += a;
        }
        if (f0 < 15u) srt[st0 + r0] = (unsigned short)(tap0 << 6);
        if (f1 < 15u) srt[st1 + r1] = (unsigned short)(tap1 << 6);
        if (f2 < 15u) srt[st2 + r2] = (unsigned short)(tap2 << 6);

        // main accumulate: per chunk-of-4: one b64 srt read + 4 b32 w reads + pairwise fp64 adds
        double run = 0.0, cvv = 0.0;
        int tc = 127;
        float ser[15];
        int A = 0;                               // aligned bucket start
        #pragma unroll
        for (int t = 0; t < 15; ++t) {
            int k = kt[t];
            for (int q = 0; q < k; q += 4) {
                uint2 pr = *(const uint2*)(srt + A + q);     // 4 sorted entries, broadcast
                unsigned e0 = pr.x & 0xFFFFu, e1 = pr.x >> 16;
                unsigned e2 = pr.y & 0xFFFFu, e3 = pr.y >> 16;
                // pad slots hold garbage: clamp address, predicate addend
                e0 = min(e0, 9536u); e1 = min(e1, 9536u);
                e2 = min(e2, 9536u); e3 = min(e3, 9536u);
                float wa = w_lds[e0 + lane];
                float wb = w_lds[e1 + lane];
                float wcf = w_lds[e2 + lane];
                float wd = w_lds[e3 + lane];
                double p0 = (double)wa;                       // q+0 < k always
                double p1 = (q + 1 < k) ? (double)wb : 0.0;
                double p2 = (q + 2 < k) ? (double)wcf : 0.0;
                double p3 = (q + 3 < k) ? (double)wd : 0.0;
                run += ((p0 + p1) + (p2 + p3));
            }
            A += (k + 3) & ~3;
            ser[t] = (float)run;
            bool cross_now = (tc == 127) && (run >= DTHRESH);
            if (cross_now) { tc = t; cvv = run; }            // cndmask, no branch
        }

        // cross-lane: e = min crossing time; winner = max cvv among tc==e, first-lane tie
        int e = tc;
        #pragma unroll
        for (int off = 32; off >= 1; off >>= 1) e = min(e, __shfl_xor(e, off));
        int wc = -1;
        double val = 0.0;
        if (e < 15) {                                    // uniform branch
            double vl = (tc == e) ? cvv : 0.0;
            double m = vl;
            #pragma unroll
            for (int off = 32; off >= 1; off >>= 1) m = fmax(m, __shfl_xor(m, off));
            unsigned long long mk = __ballot(vl == m);
            wc = __ffsll(mk) - 1;
            val = m;

            // winner's series -> lanes 0..14 via shfl, zero before crossing
            float ov = 0.0f;
            #pragma unroll
            for (int t = 0; t < 15; ++t) {
                float sv = __shfl(ser[t], wc);
                if (lane == t) ov = sv;
            }
            if (lane < e) ov = 0.0f;                     // monotone: below thresh before e
            if (lane < 15) series_ws[p * 16 + lane] = ov;
        }
        if (lane == 0) {
            winc_ws[p] = (int8_t)wc;
            nmap_ws[p] = (uint8_t)(wc >= 0 ? (15 - e) : 0);
            if (wc >= 0) val_ws[p] = val;
        }
    }
}

// ---------------- K3 (fused): block 0 = sequential 5-round k-winners; blocks 1.. = expand ----------------
// No big static LDS (would cut expand occupancy). kwin reads winc/nmap/val from L2.
__global__ __launch_bounds__(1024) void kwin_expand_kernel(
        const int8_t* __restrict__ winc, const uint8_t* __restrict__ nmap,
        const double* __restrict__ val, const float* __restrict__ series,
        float* __restrict__ spk, float* __restrict__ pot, float* __restrict__ outw)
{
    int tid = threadIdx.x;
    if (blockIdx.x != 0) {
        // ---- expand path: winner map -> full spk/pot (coalesced float4) ----
        int idx4 = (blockIdx.x - 1) * 1024 + tid;    // < 15,728,640
        int w4 = idx4 & 63;
        int h  = (idx4 >> 6) & 255;
        int c  = (idx4 >> 14) & 63;
        int t  = idx4 >> 20;
        int pbase = h * W + (w4 << 2);
        uint32_t wcs = *reinterpret_cast<const uint32_t*>(winc + pbase);
        vfloat4 pv = (vfloat4)(0.0f);
        vfloat4 sv = (vfloat4)(0.0f);
        #pragma unroll
        for (int e2 = 0; e2 < 4; ++e2) {
            int8_t wcb = (int8_t)((wcs >> (8 * e2)) & 0xFFu);
            if ((int)wcb == c) {
                float xv = series[(size_t)(pbase + e2) * 16 + t];
                pv[e2] = xv;
                sv[e2] = (xv > 0.f) ? 1.0f : 0.0f;
            }
        }
        reinterpret_cast<vfloat4*>(spk)[idx4] = sv;
        reinterpret_cast<vfloat4*>(pot)[idx4] = pv;
        return;
    }

    // ---- kwin path: block 0 only ----
    __shared__ double rv_lds[16];
    __shared__ unsigned ri_lds[16];
    __shared__ double v_lds;
    __shared__ int win_c[5], win_h[5], win_w[5];
    int lane = tid & 63, wvi = tid >> 6;

    // phase 1: v = 15 * max winner val
    double mv = 0.0;
    for (int k = 0; k < 64; ++k) {
        int p = (k << 10) + tid;                 // coalesced
        if (winc[p] >= 0) mv = fmax(mv, val[p]);
    }
    #pragma unroll
    for (int off = 32; off >= 1; off >>= 1) mv = fmax(mv, __shfl_xor(mv, off));
    if (lane == 0) rv_lds[wvi] = mv;
    __syncthreads();
    if (tid == 0) {
        double m = rv_lds[0];
        for (int i = 1; i < 16; ++i) m = fmax(m, rv_lds[i]);
        v_lds = 15.0 * m;
    }
    __syncthreads();
    double v = v_lds;

    for (int r = 0; r < 5; ++r) {
        // previous winners into registers
        int pc[5], ph[5], pw[5];
        #pragma unroll
        for (int j = 0; j < 5; ++j) { pc[j] = (j < r) ? win_c[j] : -99;
                                      ph[j] = (j < r) ? win_h[j] : -99;
                                      pw[j] = (j < r) ? win_w[j] : -99; }
        double bv = -1.0;
        unsigned bi = 0xFFFFFFFFu;
        for (int k = 0; k < 64; ++k) {
            int p = (k << 10) + tid;
            int c = winc[p];
            bool alive = (c >= 0);
            int hh = p >> 8, ww = p & 255;
            #pragma unroll
            for (int j = 0; j < 5; ++j) {
                bool kill = (c == pc[j]) ||
                            (hh >= ph[j] - 3 && hh <= ph[j] + 3 &&
                             ww >= pw[j] - 3 && ww <= pw[j] + 3);
                alive = alive && !kill;
            }
            if (alive) {
                double tot = (double)nmap[p] * (val[p] + v);
                unsigned fi = ((unsigned)c << 16) | (unsigned)p;   // c-major flat index
                if (tot > bv || (tot == bv && fi < bi)) { bv = tot; bi = fi; }
            }
        }
        #pragma unroll
        for (int off = 32; off >= 1; off >>= 1) {
            double ov = __shfl_xor(bv, off);
            unsigned oi = __shfl_xor(bi, off);
            if (ov > bv || (ov == bv && oi < bi)) { bv = ov; bi = oi; }
        }
        if (lane == 0) { rv_lds[wvi] = bv; ri_lds[wvi] = bi; }
        __syncthreads();
        if (tid == 0) {
            double bbv = rv_lds[0]; unsigned bbi = ri_lds[0];
            for (int i = 1; i < 16; ++i) {
                double ov = rv_lds[i]; unsigned oi = ri_lds[i];
                if (ov > bbv || (ov == bbv && oi < bbi)) { bbv = ov; bbi = oi; }
            }
            bool valid = (bbv > 0.0);
            int c = (int)(bbi >> 16), pp = (int)(bbi & 0xFFFFu);
            int hh = pp >> 8, ww = pp & 255;
            outw[r * 3 + 0] = valid ? (float)c  : -1.0f;
            outw[r * 3 + 1] = valid ? (float)hh : -1.0f;
            outw[r * 3 + 2] = valid ? (float)ww : -1.0f;
            win_c[r] = c; win_h[r] = hh; win_w[r] = ww;  // phantom kill when invalid is inert
        }
        __syncthreads();
    }
}

extern "C" void kernel_launch(void* const* d_in, const int* in_sizes, int n_in,
                              void* d_out, int out_size, void* d_ws, size_t ws_size,
                              hipStream_t stream)
{
    if (ws_size < WS_NEED) return;

    const float* x  = (const float*)d_in[0];
    const float* w1 = (const float*)d_in[1];
    uint8_t* ws = (uint8_t*)d_ws;
    uint8_t* ftg    = ws + WS_FT;
    float*   series = (float*)(ws + WS_SERIES);
    int8_t*  winc   = (int8_t*)(ws + WS_WINC);
    uint8_t* nmap   = (uint8_t*)(ws + WS_NMAP);
    double*  val    = (double*)(ws + WS_VAL);

    float* spk  = (float*)d_out;
    float* pot  = spk + (size_t)T_STEPS * C_OUT * NPOS;
    float* outw = pot + (size_t)T_STEPS * C_OUT * NPOS;

    hipLaunchKernelGGL(ft_kernel,   dim3(1536), dim3(256),  0, stream, x, ftg);
    hipLaunchKernelGGL(conv_kernel, dim3(4096), dim3(256),  0, stream, w1, ftg, series, winc, nmap, val);
    hipLaunchKernelGGL(kwin_expand_kernel, dim3(15361), dim3(1024), 0, stream,
                       winc, nmap, val, series, spk, pot, outw);
}

// Round 7
// 896.093 us; speedup vs baseline: 1.0089x; 1.0089x over previous
//
#include <hip/hip_runtime.h>
#include <stdint.h>

static constexpr int T_STEPS = 15;
static constexpr int C_IN = 6;
static constexpr int C_OUT = 64;
static constexpr int H = 256;
static constexpr int W = 256;
static constexpr int NPOS = H * W;            // 65536
static constexpr int NTAP = 150;              // 6*5*5
#define DTHRESH 15.0

typedef float vfloat4 __attribute__((ext_vector_type(4)));

// workspace layout (bytes)
static constexpr size_t WS_FT     = 0;                              // uint8 [C_IN*NPOS]
static constexpr size_t WS_SERIES = 393216;                         // float [NPOS*16]
static constexpr size_t WS_WINC   = WS_SERIES + (size_t)NPOS*16*4;  // int8  [NPOS]
static constexpr size_t WS_NMAP   = WS_WINC + (size_t)NPOS;         // uint8 [NPOS]
static constexpr size_t WS_VAL    = WS_NMAP + (size_t)NPOS;         // double[NPOS]
static constexpr size_t WS_NEED   = WS_VAL + (size_t)NPOS*8;

// ---------------- K1: first-spike-time map ----------------
__global__ __launch_bounds__(256) void ft_kernel(const float* __restrict__ x,
                                                 uint8_t* __restrict__ ft) {
    int i = blockIdx.x * 256 + threadIdx.x;
    if (i >= C_IN * NPOS) return;
    int f = 15;
    #pragma unroll
    for (int t = T_STEPS - 1; t >= 0; --t) {
        if (x[(size_t)t * (C_IN * NPOS) + i] > 0.0f) f = t;
    }
    ft[i] = (uint8_t)f;
}

// ---------------- K2: per-position conv-as-sorted-accumulate + pointwise WTA ----------------
// One wave per (h,w); lane = output channel. Block = 4 waves, 16 consecutive w.
// LDS: 38400 + 600 + 256 + 1600 = 40856 B -> 4 blocks/CU (163,424 <= 163,840).
__global__ __launch_bounds__(256, 4) void conv_kernel(
        const float* __restrict__ w1, const uint8_t* __restrict__ ftg,
        float* __restrict__ series_ws, int8_t* __restrict__ winc_ws,
        uint8_t* __restrict__ nmap_ws, double* __restrict__ val_ws)
{
    __shared__ float w_lds[NTAP * 64];                       // [tap][o], stride-1 across lanes
    __shared__ uint8_t ft_lds[6 * 5 * 20];                   // [c][kh][col 0..19]
    __shared__ alignas(16) unsigned cnt_lds[4][16];          // per-wave
    __shared__ alignas(16) unsigned short sorted_lds[4][200];// per-wave, 4-aligned buckets

    int tid = threadIdx.x;
    int bid = blockIdx.x;                        // 0..4095
    int h  = bid >> 4;
    int w0 = (bid & 15) << 4;

    // stage weights transposed: w_lds[tap*64 + o] = w1[o*150 + tap] (coalesced reads)
    for (int i = tid; i < C_OUT * NTAP; i += 256) {
        int o = i / NTAP;
        int tap = i - o * NTAP;
        w_lds[tap * 64 + o] = w1[i];
    }
    // stage ft tile with pad-of-15 (never spikes) outside the image
    for (int i = tid; i < 600; i += 256) {
        int c = i / 100;
        int r = i - c * 100;
        int kh = r / 20;
        int j  = r - kh * 20;
        int gh = h - 2 + kh;
        int gw = w0 - 2 + j;
        uint8_t v = 15;
        if (gh >= 0 && gh < H && gw >= 0 && gw < W) v = ftg[c * NPOS + gh * W + gw];
        ft_lds[(c * 5 + kh) * 20 + j] = v;
    }
    __syncthreads();   // the ONLY block barrier

    int lane = tid & 63;
    int wvi  = tid >> 6;
    unsigned* cnt = cnt_lds[wvi];
    unsigned short* srt = sorted_lds[wvi];

    for (int iter = 0; iter < 4; ++iter) {
        int xl = iter * 4 + wvi;                 // local col 0..15
        int p  = h * W + w0 + xl;

        if (lane < 16) cnt[lane] = 0;            // wave-private, no barrier

        // counting sort of the 150 taps by first-spike time (3 tap slots per lane)
        int tap0 = lane, tap1 = lane + 64, tap2 = lane + 128;
        auto ftv = [&](int tap) -> unsigned {
            int c = tap / 25;
            int r = tap - c * 25;
            int kh = r / 5;
            int kw = r - kh * 5;
            return ft_lds[(c * 5 + kh) * 20 + xl + kw];
        };
        unsigned f0 = ftv(tap0);
        unsigned f1 = ftv(tap1);
        unsigned f2 = (tap2 < NTAP) ? ftv(tap2) : 15u;
        unsigned r0 = 0, r1 = 0, r2 = 0;
        if (f0 < 15u) r0 = atomicAdd(&cnt[f0], 1u);
        if (f1 < 15u) r1 = atomicAdd(&cnt[f1], 1u);
        if (f2 < 15u) r2 = atomicAdd(&cnt[f2], 1u);

        // read all 16 counts via 4 vector loads (broadcast)
        uint4 c4[4];
        #pragma unroll
        for (int i = 0; i < 4; ++i) c4[i] = ((const uint4*)cnt)[i];
        unsigned cv_t[16];
        #pragma unroll
        for (int i = 0; i < 4; ++i) {
            cv_t[4*i+0] = c4[i].x; cv_t[4*i+1] = c4[i].y;
            cv_t[4*i+2] = c4[i].z; cv_t[4*i+3] = c4[i].w;
        }
        int kt[15];
        #pragma unroll
        for (int t = 0; t < 15; ++t) kt[t] = (int)__builtin_amdgcn_readfirstlane(cv_t[t]);

        // aligned-4 bucket starts: per-lane predicated prefix of align4(counts)
        unsigned st0 = 0, st1 = 0, st2 = 0;
        #pragma unroll
        for (int t = 0; t < 15; ++t) {
            unsigned a = (cv_t[t] + 3u) & ~3u;
            if ((unsigned)t < f0) st0 += a;
            if ((unsigned)t < f1) st1 += a;
            if ((unsigned)t < f2) st2 += a;
        }
        if (f0 < 15u) srt[st0 + r0] = (unsigned short)(tap0 << 6);
        if (f1 < 15u) srt[st1 + r1] = (unsigned short)(tap1 << 6);
        if (f2 < 15u) srt[st2 + r2] = (unsigned short)(tap2 << 6);

        // main accumulate: per chunk-of-4: one b64 srt read + 4 b32 w reads + pairwise fp64 adds
        double run = 0.0, cvv = 0.0;
        int tc = 127;
        float ser[15];
        int A = 0;                               // aligned bucket start
        #pragma unroll
        for (int t = 0; t < 15; ++t) {
            int k = kt[t];
            for (int q = 0; q < k; q += 4) {
                uint2 pr = *(const uint2*)(srt + A + q);     // 4 sorted entries, broadcast
                unsigned e0 = pr.x & 0xFFFFu, e1 = pr.x >> 16;
                unsigned e2 = pr.y & 0xFFFFu, e3 = pr.y >> 16;
                // pad slots hold garbage: clamp address, predicate addend
                e0 = min(e0, 9536u); e1 = min(e1, 9536u);
                e2 = min(e2, 9536u); e3 = min(e3, 9536u);
                float wa = w_lds[e0 + lane];
                float wb = w_lds[e1 + lane];
                float wcf = w_lds[e2 + lane];
                float wd = w_lds[e3 + lane];
                double p0 = (double)wa;                       // q+0 < k always
                double p1 = (q + 1 < k) ? (double)wb : 0.0;
                double p2 = (q + 2 < k) ? (double)wcf : 0.0;
                double p3 = (q + 3 < k) ? (double)wd : 0.0;
                run += ((p0 + p1) + (p2 + p3));
            }
            A += (k + 3) & ~3;
            ser[t] = (float)run;
            bool cross_now = (tc == 127) && (run >= DTHRESH);
            if (cross_now) { tc = t; cvv = run; }            // cndmask, no branch
        }

        // cross-lane: e = min crossing time; winner = max cvv among tc==e, first-lane tie
        int e = tc;
        #pragma unroll
        for (int off = 32; off >= 1; off >>= 1) e = min(e, __shfl_xor(e, off));
        int wc = -1;
        double val = 0.0;
        if (e < 15) {                                    // uniform branch
            double vl = (tc == e) ? cvv : 0.0;
            double m = vl;
            #pragma unroll
            for (int off = 32; off >= 1; off >>= 1) m = fmax(m, __shfl_xor(m, off));
            unsigned long long mk = __ballot(vl == m);
            wc = __ffsll(mk) - 1;
            val = m;

            // winner's series -> lanes 0..14 via shfl, zero before crossing
            float ov = 0.0f;
            #pragma unroll
            for (int t = 0; t < 15; ++t) {
                float sv = __shfl(ser[t], wc);
                if (lane == t) ov = sv;
            }
            if (lane < e) ov = 0.0f;                     // monotone: below thresh before e
            if (lane < 15) series_ws[p * 16 + lane] = ov;
        }
        if (lane == 0) {
            winc_ws[p] = (int8_t)wc;
            nmap_ws[p] = (uint8_t)(wc >= 0 ? (15 - e) : 0);
            if (wc >= 0) val_ws[p] = val;
        }
    }
}

// ---------------- K3 (fused): block 0 = sequential 5-round k-winners; blocks 1.. = expand ----------------
// __launch_bounds__(1024, 8): forces VGPR <= 64 so expand blocks keep 2 blocks/CU (32 waves)
// regardless of kwin-path register pressure. kwin loops unroll-capped to fit the budget;
// any residual kwin slowdown is hidden under expand's ~88 us.
__global__ __launch_bounds__(1024, 8) void kwin_expand_kernel(
        const int8_t* __restrict__ winc, const uint8_t* __restrict__ nmap,
        const double* __restrict__ val, const float* __restrict__ series,
        float* __restrict__ spk, float* __restrict__ pot, float* __restrict__ outw)
{
    int tid = threadIdx.x;
    if (blockIdx.x != 0) {
        // ---- expand path: winner map -> full spk/pot (coalesced float4) ----
        int idx4 = (blockIdx.x - 1) * 1024 + tid;    // < 15,728,640
        int w4 = idx4 & 63;
        int h  = (idx4 >> 6) & 255;
        int c  = (idx4 >> 14) & 63;
        int t  = idx4 >> 20;
        int pbase = h * W + (w4 << 2);
        uint32_t wcs = *reinterpret_cast<const uint32_t*>(winc + pbase);
        vfloat4 pv = (vfloat4)(0.0f);
        vfloat4 sv = (vfloat4)(0.0f);
        #pragma unroll
        for (int e2 = 0; e2 < 4; ++e2) {
            int8_t wcb = (int8_t)((wcs >> (8 * e2)) & 0xFFu);
            if ((int)wcb == c) {
                float xv = series[(size_t)(pbase + e2) * 16 + t];
                pv[e2] = xv;
                sv[e2] = (xv > 0.f) ? 1.0f : 0.0f;
            }
        }
        reinterpret_cast<vfloat4*>(spk)[idx4] = sv;
        reinterpret_cast<vfloat4*>(pot)[idx4] = pv;
        return;
    }

    // ---- kwin path: block 0 only ----
    __shared__ double rv_lds[16];
    __shared__ unsigned ri_lds[16];
    __shared__ double v_lds;
    __shared__ int win_c[5], win_h[5], win_w[5];
    int lane = tid & 63, wvi = tid >> 6;

    // phase 1: v = 15 * max winner val
    double mv = 0.0;
    #pragma unroll 4
    for (int k = 0; k < 64; ++k) {
        int p = (k << 10) + tid;                 // coalesced
        if (winc[p] >= 0) mv = fmax(mv, val[p]);
    }
    #pragma unroll
    for (int off = 32; off >= 1; off >>= 1) mv = fmax(mv, __shfl_xor(mv, off));
    if (lane == 0) rv_lds[wvi] = mv;
    __syncthreads();
    if (tid == 0) {
        double m = rv_lds[0];
        for (int i = 1; i < 16; ++i) m = fmax(m, rv_lds[i]);
        v_lds = 15.0 * m;
    }
    __syncthreads();
    double v = v_lds;

    for (int r = 0; r < 5; ++r) {
        // previous winners into registers
        int pc[5], ph[5], pw[5];
        #pragma unroll
        for (int j = 0; j < 5; ++j) { pc[j] = (j < r) ? win_c[j] : -99;
                                      ph[j] = (j < r) ? win_h[j] : -99;
                                      pw[j] = (j < r) ? win_w[j] : -99; }
        double bv = -1.0;
        unsigned bi = 0xFFFFFFFFu;
        #pragma unroll 4
        for (int k = 0; k < 64; ++k) {
            int p = (k << 10) + tid;
            int c = winc[p];
            bool alive = (c >= 0);
            int hh = p >> 8, ww = p & 255;
            #pragma unroll
            for (int j = 0; j < 5; ++j) {
                bool kill = (c == pc[j]) ||
                            (hh >= ph[j] - 3 && hh <= ph[j] + 3 &&
                             ww >= pw[j] - 3 && ww <= pw[j] + 3);
                alive = alive && !kill;
            }
            if (alive) {
                double tot = (double)nmap[p] * (val[p] + v);
                unsigned fi = ((unsigned)c << 16) | (unsigned)p;   // c-major flat index
                if (tot > bv || (tot == bv && fi < bi)) { bv = tot; bi = fi; }
            }
        }
        #pragma unroll
        for (int off = 32; off >= 1; off >>= 1) {
            double ov = __shfl_xor(bv, off);
            unsigned oi = __shfl_xor(bi, off);
            if (ov > bv || (ov == bv && oi < bi)) { bv = ov; bi = oi; }
        }
        if (lane == 0) { rv_lds[wvi] = bv; ri_lds[wvi] = bi; }
        __syncthreads();
        if (tid == 0) {
            double bbv = rv_lds[0]; unsigned bbi = ri_lds[0];
            for (int i = 1; i < 16; ++i) {
                double ov = rv_lds[i]; unsigned oi = ri_lds[i];
                if (ov > bbv || (ov == bbv && oi < bbi)) { bbv = ov; bbi = oi; }
            }
            bool valid = (bbv > 0.0);
            int c = (int)(bbi >> 16), pp = (int)(bbi & 0xFFFFu);
            int hh = pp >> 8, ww = pp & 255;
            outw[r * 3 + 0] = valid ? (float)c  : -1.0f;
            outw[r * 3 + 1] = valid ? (float)hh : -1.0f;
            outw[r * 3 + 2] = valid ? (float)ww : -1.0f;
            win_c[r] = c; win_h[r] = hh; win_w[r] = ww;  // phantom kill when invalid is inert
        }
        __syncthreads();
    }
}

extern "C" void kernel_launch(void* const* d_in, const int* in_sizes, int n_in,
                              void* d_out, int out_size, void* d_ws, size_t ws_size,
                              hipStream_t stream)
{
    if (ws_size < WS_NEED) return;

    const float* x  = (const float*)d_in[0];
    const float* w1 = (const float*)d_in[1];
    uint8_t* ws = (uint8_t*)d_ws;
    uint8_t* ftg    = ws + WS_FT;
    float*   series = (float*)(ws + WS_SERIES);
    int8_t*  winc   = (int8_t*)(ws + WS_WINC);
    uint8_t* nmap   = (uint8_t*)(ws + WS_NMAP);
    double*  val    = (double*)(ws + WS_VAL);

    float* spk  = (float*)d_out;
    float* pot  = spk + (size_t)T_STEPS * C_OUT * NPOS;
    float* outw = pot + (size_t)T_STEPS * C_OUT * NPOS;

    hipLaunchKernelGGL(ft_kernel,   dim3(1536), dim3(256),  0, stream, x, ftg);
    hipLaunchKernelGGL(conv_kernel, dim3(4096), dim3(256),  0, stream, w1, ftg, series, winc, nmap, val);
    hipLaunchKernelGGL(kwin_expand_kernel, dim3(15361), dim3(1024), 0, stream,
                       winc, nmap, val, series, spk, pot, outw);
}

// Round 8
// 868.840 us; speedup vs baseline: 1.0406x; 1.0314x over previous
//
#include <hip/hip_runtime.h>
#include <stdint.h>

static constexpr int T_STEPS = 15;
static constexpr int C_IN = 6;
static constexpr int C_OUT = 64;
static constexpr int H = 256;
static constexpr int W = 256;
static constexpr int NPOS = H * W;            // 65536
static constexpr int NTAP = 150;              // 6*5*5
#define DTHRESH 15.0

typedef float vfloat4 __attribute__((ext_vector_type(4)));

// workspace layout (bytes)
static constexpr size_t WS_FT     = 0;                              // uint8 [C_IN*NPOS]
static constexpr size_t WS_SERIES = 393216;                         // float [NPOS*16]
static constexpr size_t WS_WINC   = WS_SERIES + (size_t)NPOS*16*4;  // int8  [NPOS]
static constexpr size_t WS_NMAP   = WS_WINC + (size_t)NPOS;         // uint8 [NPOS]
static constexpr size_t WS_VAL    = WS_NMAP + (size_t)NPOS;         // double[NPOS]
static constexpr size_t WS_NEED   = WS_VAL + (size_t)NPOS*8;

// ---------------- K1: first-spike-time map ----------------
__global__ __launch_bounds__(256) void ft_kernel(const float* __restrict__ x,
                                                 uint8_t* __restrict__ ft) {
    int i = blockIdx.x * 256 + threadIdx.x;
    if (i >= C_IN * NPOS) return;
    int f = 15;
    #pragma unroll
    for (int t = T_STEPS - 1; t >= 0; --t) {
        if (x[(size_t)t * (C_IN * NPOS) + i] > 0.0f) f = t;
    }
    ft[i] = (uint8_t)f;
}

// ---------------- K2: per-position conv-as-sorted-accumulate + pointwise WTA ----------------
// One wave per (h,w); lane = output channel. Block = 4 waves, 16 consecutive w.
// LDS: 38400 + 600 + 256 + 1600 = 40856 B -> 4 blocks/CU (163,424 <= 163,840).
__global__ __launch_bounds__(256, 4) void conv_kernel(
        const float* __restrict__ w1, const uint8_t* __restrict__ ftg,
        float* __restrict__ series_ws, int8_t* __restrict__ winc_ws,
        uint8_t* __restrict__ nmap_ws, double* __restrict__ val_ws)
{
    __shared__ float w_lds[NTAP * 64];                       // [tap][o], stride-1 across lanes
    __shared__ uint8_t ft_lds[6 * 5 * 20];                   // [c][kh][col 0..19]
    __shared__ alignas(16) unsigned cnt_lds[4][16];          // per-wave
    __shared__ alignas(16) unsigned short sorted_lds[4][200];// per-wave, 4-aligned buckets

    int tid = threadIdx.x;
    int bid = blockIdx.x;                        // 0..4095
    int h  = bid >> 4;
    int w0 = (bid & 15) << 4;

    // stage weights transposed: w_lds[tap*64 + o] = w1[o*150 + tap] (coalesced reads)
    for (int i = tid; i < C_OUT * NTAP; i += 256) {
        int o = i / NTAP;
        int tap = i - o * NTAP;
        w_lds[tap * 64 + o] = w1[i];
    }
    // stage ft tile with pad-of-15 (never spikes) outside the image
    for (int i = tid; i < 600; i += 256) {
        int c = i / 100;
        int r = i - c * 100;
        int kh = r / 20;
        int j  = r - kh * 20;
        int gh = h - 2 + kh;
        int gw = w0 - 2 + j;
        uint8_t v = 15;
        if (gh >= 0 && gh < H && gw >= 0 && gw < W) v = ftg[c * NPOS + gh * W + gw];
        ft_lds[(c * 5 + kh) * 20 + j] = v;
    }
    __syncthreads();   // the ONLY block barrier

    int lane = tid & 63;
    int wvi  = tid >> 6;
    unsigned* cnt = cnt_lds[wvi];
    unsigned short* srt = sorted_lds[wvi];

    for (int iter = 0; iter < 4; ++iter) {
        int xl = iter * 4 + wvi;                 // local col 0..15
        int p  = h * W + w0 + xl;

        if (lane < 16) cnt[lane] = 0;            // wave-private, no barrier

        // counting sort of the 150 taps by first-spike time (3 tap slots per lane)
        int tap0 = lane, tap1 = lane + 64, tap2 = lane + 128;
        auto ftv = [&](int tap) -> unsigned {
            int c = tap / 25;
            int r = tap - c * 25;
            int kh = r / 5;
            int kw = r - kh * 5;
            return ft_lds[(c * 5 + kh) * 20 + xl + kw];
        };
        unsigned f0 = ftv(tap0);
        unsigned f1 = ftv(tap1);
        unsigned f2 = (tap2 < NTAP) ? ftv(tap2) : 15u;
        unsigned r0 = 0, r1 = 0, r2 = 0;
        if (f0 < 15u) r0 = atomicAdd(&cnt[f0], 1u);
        if (f1 < 15u) r1 = atomicAdd(&cnt[f1], 1u);
        if (f2 < 15u) r2 = atomicAdd(&cnt[f2], 1u);

        // read all 16 counts via 4 vector loads (broadcast)
        uint4 c4[4];
        #pragma unroll
        for (int i = 0; i < 4; ++i) c4[i] = ((const uint4*)cnt)[i];
        unsigned cv_t[16];
        #pragma unroll
        for (int i = 0; i < 4; ++i) {
            cv_t[4*i+0] = c4[i].x; cv_t[4*i+1] = c4[i].y;
            cv_t[4*i+2] = c4[i].z; cv_t[4*i+3] = c4[i].w;
        }
        int kt[15];
        #pragma unroll
        for (int t = 0; t < 15; ++t) kt[t] = (int)__builtin_amdgcn_readfirstlane(cv_t[t]);

        // aligned-4 bucket starts: per-lane predicated prefix of align4(counts)
        unsigned st0 = 0, st1 = 0, st2 = 0;
        #pragma unroll
        for (int t = 0; t < 15; ++t) {
            unsigned a = (cv_t[t] + 3u) & ~3u;
            if ((unsigned)t < f0) st0 += a;
            if ((unsigned)t < f1) st1 += a;
            if ((unsigned)t < f2) st2 += a;
        }
        if (f0 < 15u) srt[st0 + r0] = (unsigned short)(tap0 << 6);
        if (f1 < 15u) srt[st1 + r1] = (unsigned short)(tap1 << 6);
        if (f2 < 15u) srt[st2 + r2] = (unsigned short)(tap2 << 6);

        // main accumulate: per chunk-of-4: one b64 srt read + 4 b32 w reads + pairwise fp64 adds
        double run = 0.0, cvv = 0.0;
        int tc = 127;
        float ser[15];
        int A = 0;                               // aligned bucket start
        #pragma unroll
        for (int t = 0; t < 15; ++t) {
            int k = kt[t];
            for (int q = 0; q < k; q += 4) {
                uint2 pr = *(const uint2*)(srt + A + q);     // 4 sorted entries, broadcast
                unsigned e0 = pr.x & 0xFFFFu, e1 = pr.x >> 16;
                unsigned e2 = pr.y & 0xFFFFu, e3 = pr.y >> 16;
                // pad slots hold garbage: clamp address, predicate addend
                e0 = min(e0, 9536u); e1 = min(e1, 9536u);
                e2 = min(e2, 9536u); e3 = min(e3, 9536u);
                float wa = w_lds[e0 + lane];
                float wb = w_lds[e1 + lane];
                float wcf = w_lds[e2 + lane];
                float wd = w_lds[e3 + lane];
                double p0 = (double)wa;                       // q+0 < k always
                double p1 = (q + 1 < k) ? (double)wb : 0.0;
                double p2 = (q + 2 < k) ? (double)wcf : 0.0;
                double p3 = (q + 3 < k) ? (double)wd : 0.0;
                run += ((p0 + p1) + (p2 + p3));
            }
            A += (k + 3) & ~3;
            ser[t] = (float)run;
            bool cross_now = (tc == 127) && (run >= DTHRESH);
            if (cross_now) { tc = t; cvv = run; }            // cndmask, no branch
        }

        // cross-lane: e = min crossing time; winner = max cvv among tc==e, first-lane tie
        int e = tc;
        #pragma unroll
        for (int off = 32; off >= 1; off >>= 1) e = min(e, __shfl_xor(e, off));
        int wc = -1;
        double val = 0.0;
        if (e < 15) {                                    // uniform branch
            double vl = (tc == e) ? cvv : 0.0;
            double m = vl;
            #pragma unroll
            for (int off = 32; off >= 1; off >>= 1) m = fmax(m, __shfl_xor(m, off));
            unsigned long long mk = __ballot(vl == m);
            wc = __ffsll(mk) - 1;
            val = m;

            // winner's series -> lanes 0..14 via shfl, zero before crossing
            float ov = 0.0f;
            #pragma unroll
            for (int t = 0; t < 15; ++t) {
                float sv = __shfl(ser[t], wc);
                if (lane == t) ov = sv;
            }
            if (lane < e) ov = 0.0f;                     // monotone: below thresh before e
            if (lane < 15) series_ws[p * 16 + lane] = ov;
        }
        if (lane == 0) {
            winc_ws[p] = (int8_t)wc;
            nmap_ws[p] = (uint8_t)(wc >= 0 ? (15 - e) : 0);
            if (wc >= 0) val_ws[p] = val;
        }
    }
}

// ---------------- K3: sequential 5-round k-winners (single block; winc/nmap LDS-cached) ----------------
__global__ __launch_bounds__(1024) void kwin_kernel(
        const int8_t* __restrict__ winc, const uint8_t* __restrict__ nmap,
        const double* __restrict__ val, float* __restrict__ outw)
{
    __shared__ int8_t  winc_l[NPOS];             // 64 KB
    __shared__ uint8_t nmap_l[NPOS];             // 64 KB
    __shared__ double rv_lds[16];
    __shared__ unsigned ri_lds[16];
    __shared__ double v_lds;
    __shared__ int win_c[5], win_h[5], win_w[5];
    int tid = threadIdx.x, lane = tid & 63, wvi = tid >> 6;

    // vectorized LDS fill: 128 KB total, 4x int4 per thread per array
    {
        const int4* ws4 = (const int4*)winc;
        int4* wd4 = (int4*)winc_l;
        const int4* ns4 = (const int4*)nmap;
        int4* nd4 = (int4*)nmap_l;
        #pragma unroll
        for (int i = 0; i < NPOS / 16 / 1024; ++i) {
            wd4[tid + (i << 10)] = ws4[tid + (i << 10)];
            nd4[tid + (i << 10)] = ns4[tid + (i << 10)];
        }
    }
    __syncthreads();

    // phase 1: v = 15 * max winner val
    double mv = 0.0;
    for (int k = 0; k < 64; ++k) {
        int p = (k << 10) + tid;                 // coalesced
        if (winc_l[p] >= 0) mv = fmax(mv, val[p]);
    }
    #pragma unroll
    for (int off = 32; off >= 1; off >>= 1) mv = fmax(mv, __shfl_xor(mv, off));
    if (lane == 0) rv_lds[wvi] = mv;
    __syncthreads();
    if (tid == 0) {
        double m = rv_lds[0];
        for (int i = 1; i < 16; ++i) m = fmax(m, rv_lds[i]);
        v_lds = 15.0 * m;
    }
    __syncthreads();
    double v = v_lds;

    for (int r = 0; r < 5; ++r) {
        // previous winners into registers
        int pc[5], ph[5], pw[5];
        #pragma unroll
        for (int j = 0; j < 5; ++j) { pc[j] = (j < r) ? win_c[j] : -99;
                                      ph[j] = (j < r) ? win_h[j] : -99;
                                      pw[j] = (j < r) ? win_w[j] : -99; }
        double bv = -1.0;
        unsigned bi = 0xFFFFFFFFu;
        for (int k = 0; k < 64; ++k) {
            int p = (k << 10) + tid;
            int c = winc_l[p];
            bool alive = (c >= 0);
            int hh = p >> 8, ww = p & 255;
            #pragma unroll
            for (int j = 0; j < 5; ++j) {
                bool kill = (c == pc[j]) ||
                            (hh >= ph[j] - 3 && hh <= ph[j] + 3 &&
                             ww >= pw[j] - 3 && ww <= pw[j] + 3);
                alive = alive && !kill;
            }
            if (alive) {
                double tot = (double)nmap_l[p] * (val[p] + v);
                unsigned fi = ((unsigned)c << 16) | (unsigned)p;   // c-major flat index
                if (tot > bv || (tot == bv && fi < bi)) { bv = tot; bi = fi; }
            }
        }
        #pragma unroll
        for (int off = 32; off >= 1; off >>= 1) {
            double ov = __shfl_xor(bv, off);
            unsigned oi = __shfl_xor(bi, off);
            if (ov > bv || (ov == bv && oi < bi)) { bv = ov; bi = oi; }
        }
        if (lane == 0) { rv_lds[wvi] = bv; ri_lds[wvi] = bi; }
        __syncthreads();
        if (tid == 0) {
            double bbv = rv_lds[0]; unsigned bbi = ri_lds[0];
            for (int i = 1; i < 16; ++i) {
                double ov = rv_lds[i]; unsigned oi = ri_lds[i];
                if (ov > bbv || (ov == bbv && oi < bbi)) { bbv = ov; bbi = oi; }
            }
            bool valid = (bbv > 0.0);
            int c = (int)(bbi >> 16), pp = (int)(bbi & 0xFFFFu);
            int hh = pp >> 8, ww = pp & 255;
            outw[r * 3 + 0] = valid ? (float)c  : -1.0f;
            outw[r * 3 + 1] = valid ? (float)hh : -1.0f;
            outw[r * 3 + 2] = valid ? (float)ww : -1.0f;
            win_c[r] = c; win_h[r] = hh; win_w[r] = ww;  // phantom kill when invalid is inert
        }
        __syncthreads();
    }
}

// ---------------- K4: expand winner map to full spk/pot (coalesced float4, plain stores) ----------------
__global__ __launch_bounds__(256) void expand_kernel(
        const int8_t* __restrict__ winc, const float* __restrict__ series,
        float* __restrict__ spk, float* __restrict__ pot)
{
    int idx4 = blockIdx.x * 256 + threadIdx.x;   // < 15,728,640
    int w4 = idx4 & 63;
    int h  = (idx4 >> 6) & 255;
    int c  = (idx4 >> 14) & 63;
    int t  = idx4 >> 20;
    int pbase = h * W + (w4 << 2);
    uint32_t wcs = *reinterpret_cast<const uint32_t*>(winc + pbase);
    vfloat4 pv = (vfloat4)(0.0f);
    vfloat4 sv = (vfloat4)(0.0f);
    #pragma unroll
    for (int e2 = 0; e2 < 4; ++e2) {
        int8_t wcb = (int8_t)((wcs >> (8 * e2)) & 0xFFu);
        if ((int)wcb == c) {
            float xv = series[(size_t)(pbase + e2) * 16 + t];
            pv[e2] = xv;
            sv[e2] = (xv > 0.f) ? 1.0f : 0.0f;
        }
    }
    reinterpret_cast<vfloat4*>(spk)[idx4] = sv;
    reinterpret_cast<vfloat4*>(pot)[idx4] = pv;
}

extern "C" void kernel_launch(void* const* d_in, const int* in_sizes, int n_in,
                              void* d_out, int out_size, void* d_ws, size_t ws_size,
                              hipStream_t stream)
{
    if (ws_size < WS_NEED) return;

    const float* x  = (const float*)d_in[0];
    const float* w1 = (const float*)d_in[1];
    uint8_t* ws = (uint8_t*)d_ws;
    uint8_t* ftg    = ws + WS_FT;
    float*   series = (float*)(ws + WS_SERIES);
    int8_t*  winc   = (int8_t*)(ws + WS_WINC);
    uint8_t* nmap   = (uint8_t*)(ws + WS_NMAP);
    double*  val    = (double*)(ws + WS_VAL);

    float* spk  = (float*)d_out;
    float* pot  = spk + (size_t)T_STEPS * C_OUT * NPOS;
    float* outw = pot + (size_t)T_STEPS * C_OUT * NPOS;

    hipLaunchKernelGGL(ft_kernel,     dim3(1536),  dim3(256),  0, stream, x, ftg);
    hipLaunchKernelGGL(conv_kernel,   dim3(4096),  dim3(256),  0, stream, w1, ftg, series, winc, nmap, val);
    hipLaunchKernelGGL(kwin_kernel,   dim3(1),     dim3(1024), 0, stream, winc, nmap, val, outw);
    hipLaunchKernelGGL(expand_kernel, dim3(61440), dim3(256),  0, stream, winc, series, spk, pot);
}